// Round 8
// baseline (127.664 us; speedup 1.0000x reference)
//
#include <hip/hip_runtime.h>
#include <math.h>

#define POOL 7
#define FH 50
#define FW 50
#define FC 1024
#define FC4 (FC / 4)      // 256 vf4 per spatial cell
#define CHUNKS 4          // channel chunks; 64 vf4 (256 ch) per chunk
#define F4C 64            // vf4 per cell per chunk (one wave-wide load)

typedef float vf4 __attribute__((ext_vector_type(4)));

static __device__ __forceinline__ vf4 vmax4(vf4 a, vf4 b) {
    vf4 r;
    r.x = fmaxf(a.x, b.x);
    r.y = fmaxf(a.y, b.y);
    r.z = fmaxf(a.z, b.z);
    r.w = fmaxf(a.w, b.w);
    return r;
}

// One wave per (roi, row-bin i, chunk); computes ALL 7 column bins in one
// sweep over the row-band. ROI setup amortized 7x; ~rw independent loads
// per row issued back-to-back (7 independent fmax chains). chunk = b&3
// pins each XCD (round-robin b%8) to one 2.56 MB channel slice (L2-resident).
// 300*7 row-bands * 4 chunks / 4 waves-per-block = 2100 blocks (~8/CU).
__global__ __launch_bounds__(256) void roipool_kernel(
    const float* __restrict__ fm,     // [FH, FW, FC]
    const float* __restrict__ rois,   // [N, 4] (y1, x1, y2, x2) normalized
    float* __restrict__ out,          // [N, 7, 7, FC]
    int nrb)                          // N * 7 row-bands
{
    const int b     = blockIdx.x;
    const int chunk = b & (CHUNKS - 1);       // pinned per XCD
    const int wave  = threadIdx.x >> 6;
    const int lane  = threadIdx.x & 63;
    const int t     = (b >> 2) * 4 + wave;    // row-band id: n*7 + i
    if (t >= nrb) return;

    const int n = t / POOL;
    const int i = t - n * POOL;

    // ROI corners: truncating float->int cast, matching jnp astype(int32)
    const float4 roi = reinterpret_cast<const float4*>(rois)[n];
    const int h0 = (int)((float)FH * roi.x);
    const int w0 = (int)((float)FW * roi.y);
    const int h1 = (int)((float)FH * roi.z);
    const int w1 = (int)((float)FW * roi.w);
    const int rh = h1 - h0;
    const int rw = w1 - w0;
    const int hstep = rh / POOL;
    const int wstep = rw / POOL;

    // row-band bounds for this i (region-relative + empty-bin adjustment)
    int sh = i * hstep;
    int eh = (i < POOL - 1) ? (i + 1) * hstep : rh;
    if (sh == eh) { if (eh < rh) eh += 1; else sh -= 1; }
    const int r0 = max(0, h0 + sh);
    const int r1 = min(FH, h0 + eh);

    // column bounds for all 7 bins
    int cs[POOL], ce[POOL];
#pragma unroll
    for (int j = 0; j < POOL; ++j) {
        int sw = j * wstep;
        int ew = (j < POOL - 1) ? (j + 1) * wstep : rw;
        if (sw == ew) { if (ew < rw) ew += 1; else sw -= 1; }
        cs[j] = max(0, w0 + sw);
        ce[j] = min(FW, w0 + ew);
    }

    const int f4 = chunk * F4C + lane;        // vf4 index within cell

    vf4 acc[POOL];
#pragma unroll
    for (int j = 0; j < POOL; ++j)
        acc[j] = (vf4){-INFINITY, -INFINITY, -INFINITY, -INFINITY};

    const vf4* fm4 = reinterpret_cast<const vf4*>(fm);
    const size_t rowstride = (size_t)FW * FC4;

    for (int r = r0; r < r1; ++r) {
        const vf4* rowp = fm4 + (size_t)r * rowstride + f4;
#pragma unroll
        for (int j = 0; j < POOL; ++j) {
            for (int c = cs[j]; c < ce[j]; ++c)
                acc[j] = vmax4(acc[j], rowp[(size_t)c * FC4]);
        }
    }

    vf4* o = reinterpret_cast<vf4*>(out) + (size_t)(t * POOL) * FC4 + f4;
#pragma unroll
    for (int j = 0; j < POOL; ++j)
        __builtin_nontemporal_store(acc[j], o + (size_t)j * FC4);
}

extern "C" void kernel_launch(void* const* d_in, const int* in_sizes, int n_in,
                              void* d_out, int out_size, void* d_ws, size_t ws_size,
                              hipStream_t stream) {
    const float* features = (const float*)d_in[0];  // [1,50,50,1024]
    const float* rois     = (const float*)d_in[1];  // [N,4]
    float* out            = (float*)d_out;          // [N,7,7,1024]
    const int N = in_sizes[1] / 4;

    const int nrb = N * POOL;                       // 2100 row-bands
    // linear grid: block b -> chunk b&3 (XCD-pinned), row-bands (b>>2)*4+wave
    dim3 grid(((nrb + 3) / 4) * CHUNKS);            // 2100 blocks
    dim3 block(256);
    roipool_kernel<<<grid, block, 0, stream>>>(features, rois, out, nrb);
}

// Round 9
// 101.035 us; speedup vs baseline: 1.2636x; 1.2636x over previous
//
#include <hip/hip_runtime.h>
#include <math.h>

#define POOL 7
#define FH 50
#define FW 50
#define FC 1024
#define FC4 (FC / 4)      // 256 vf4 per spatial cell
#define CHUNKS 4          // channel chunks; 64 vf4 (256 ch) per chunk
#define F4C 64            // vf4 per cell per chunk (one wave-wide load)
#define NBLOCKS 2048      // persistent: 8 blocks/CU, 32 waves/CU resident
#define WSTRIDE 2048      // workers per chunk (512 blocks x 4 waves)

typedef float vf4 __attribute__((ext_vector_type(4)));

static __device__ __forceinline__ vf4 vmax4(vf4 a, vf4 b) {
    vf4 r;
    r.x = fmaxf(a.x, b.x);
    r.y = fmaxf(a.y, b.y);
    r.z = fmaxf(a.z, b.z);
    r.w = fmaxf(a.w, b.w);
    return r;
}

// Persistent-wave RoI max-pool, chunk/XCD-pinned.
// chunk = b&3 (XCD round-robin b%8 => XCD k always sees chunk k&3); each
// wave grid-strides over bins of its chunk (~7 bins/wave), prefetching the
// NEXT bin's ROI before processing the current bin's cells so the longest
// serial-latency load overlaps current compute. Bin math is bit-exact vs
// the reference (truncating casts + empty-bin grow/shrink).
__global__ __launch_bounds__(256) void roipool_kernel(
    const float* __restrict__ fm,     // [FH, FW, FC]
    const float* __restrict__ rois,   // [N, 4] (y1, x1, y2, x2) normalized
    float* __restrict__ out,          // [N, 7, 7, FC]
    int nbins)
{
    const int b      = blockIdx.x;
    const int chunk  = b & (CHUNKS - 1);        // pinned per XCD
    const int wave   = threadIdx.x >> 6;
    const int lane   = threadIdx.x & 63;
    const int worker = (b >> 2) * 4 + wave;     // [0, WSTRIDE) per chunk
    const int f4     = chunk * F4C + lane;      // vf4 index within cell

    const float4* rois4 = reinterpret_cast<const float4*>(rois);
    const vf4* fm4 = reinterpret_cast<const vf4*>(fm);
    const size_t rowstride = (size_t)FW * FC4;

    int gid = worker;
    if (gid >= nbins) return;

    float4 roi = rois4[gid / 49];               // first ROI

    while (gid < nbins) {
        const int next = gid + WSTRIDE;
        float4 roi_next;
        if (next < nbins) roi_next = rois4[next / 49];  // prefetch next ROI

        // ---- current bin (bit-exact bounds) ----
        const int n  = gid / 49;
        const int ij = gid - n * 49;
        const int i  = ij / 7;
        const int j  = ij - i * 7;

        const int h0 = (int)((float)FH * roi.x);
        const int w0 = (int)((float)FW * roi.y);
        const int h1 = (int)((float)FH * roi.z);
        const int w1 = (int)((float)FW * roi.w);
        const int rh = h1 - h0;
        const int rw = w1 - w0;
        const int hstep = rh / POOL;
        const int wstep = rw / POOL;

        int sh = i * hstep;
        int eh = (i < POOL - 1) ? (i + 1) * hstep : rh;
        if (sh == eh) { if (eh < rh) eh += 1; else sh -= 1; }
        int sw = j * wstep;
        int ew = (j < POOL - 1) ? (j + 1) * wstep : rw;
        if (sw == ew) { if (ew < rw) ew += 1; else sw -= 1; }

        const int r0 = max(0, h0 + sh);
        const int r1 = min(FH, h0 + eh);
        const int c0 = max(0, w0 + sw);
        const int c1 = min(FW, w0 + ew);

        vf4 acc = {-INFINITY, -INFINITY, -INFINITY, -INFINITY};

        for (int r = r0; r < r1; ++r) {
            const vf4* rp = fm4 + (size_t)r * rowstride + f4;
            int c = c0;
            for (; c + 1 < c1; c += 2) {
                vf4 a0 = rp[(size_t)c * FC4];
                vf4 a1 = rp[(size_t)(c + 1) * FC4];
                acc = vmax4(acc, vmax4(a0, a1));
            }
            if (c < c1) acc = vmax4(acc, rp[(size_t)c * FC4]);
        }

        vf4* o = reinterpret_cast<vf4*>(out) + (size_t)gid * FC4 + f4;
        __builtin_nontemporal_store(acc, o);

        roi = roi_next;
        gid = next;
    }
}

extern "C" void kernel_launch(void* const* d_in, const int* in_sizes, int n_in,
                              void* d_out, int out_size, void* d_ws, size_t ws_size,
                              hipStream_t stream) {
    const float* features = (const float*)d_in[0];  // [1,50,50,1024]
    const float* rois     = (const float*)d_in[1];  // [N,4]
    float* out            = (float*)d_out;          // [N,7,7,1024]
    const int N = in_sizes[1] / 4;

    const int nbins = N * POOL * POOL;              // 14700
    dim3 grid(NBLOCKS);                             // persistent waves
    dim3 block(256);
    roipool_kernel<<<grid, block, 0, stream>>>(features, rois, out, nbins);
}